// Round 3
// baseline (466.482 us; speedup 1.0000x reference)
//
#include <hip/hip_runtime.h>
#include <math.h>

typedef __bf16 bf16;
typedef __bf16 bf16x8 __attribute__((ext_vector_type(8)));
typedef float f32x4 __attribute__((ext_vector_type(4)));
typedef float f32x16 __attribute__((ext_vector_type(16)));
typedef unsigned int u32x4 __attribute__((ext_vector_type(4)));

__device__ __forceinline__ void load_lds16(const void* g, void* l) {
    __builtin_amdgcn_global_load_lds(
        (const __attribute__((address_space(1))) unsigned int*)g,
        (__attribute__((address_space(3))) unsigned int*)l, 16, 0, 0);
}

// ---------------------------------------------------------------------------
// prep_w2: W2 [cout][ci][tap] f32 -> B-fragment buffer for mfma_32x32x16_bf16.
// frag f = s*2 + nt  (s = K-slice 0..17: tap=s>>1, ci_base=(s&1)*16; nt = cout half)
// w2r[(f*64 + lane)*8 + j] = W2[cout = nt*32+(lane&31)][ci = ci_base+(lane>>5)*8+j][tap]
// ---------------------------------------------------------------------------
__global__ void prep_w2(const float* __restrict__ W2, bf16* __restrict__ w2r) {
    int e = blockIdx.x * 256 + threadIdx.x;     // 0..18431
    int j  = e & 7;
    int l  = (e >> 3) & 63;
    int f  = e >> 9;
    int s  = f >> 1;
    int nt = f & 1;
    int tap  = s >> 1;
    int ci   = (s & 1) * 16 + (l >> 5) * 8 + j;
    int cout = nt * 32 + (l & 31);
    w2r[e] = (bf16)W2[cout * 288 + ci * 9 + tap];
}

// ---------------------------------------------------------------------------
// prep_wl1t: Wl1 f32 [12544][128] -> bf16 transposed [128][12544]
// ---------------------------------------------------------------------------
__global__ void prep_wl1t(const float* __restrict__ Wl1, bf16* __restrict__ wl1t) {
    int n = blockIdx.y;
    int k = blockIdx.x * 256 + threadIdx.x;
    wl1t[(long)n * 12544 + k] = (bf16)Wl1[(long)k * 128 + n];
}

// ---------------------------------------------------------------------------
// conv_fused: conv1(masked,relu,VALU) + conv2(masked,relu,MFMA 32x32x16) + pool.
// One block = one image * 4 pooled rows. W2 B-frags live in 72 VGPRs per wave
// (nt = wv&1 selects 32 couts); no W2 in LDS -> 28KB LDS -> 4 blocks/CU.
// ---------------------------------------------------------------------------
__global__ __launch_bounds__(256, 4)
void conv_fused(const float* __restrict__ x, const float* __restrict__ W1,
                const float* __restrict__ b1, const bf16* __restrict__ w2r,
                const float* __restrict__ b2, bf16* __restrict__ pooled)
{
    __shared__ __attribute__((aligned(16))) bf16  h1s[10 * 30 * 32];  // swizzled
    __shared__ __attribute__((aligned(16))) float xs[12 * 32];
    __shared__ __attribute__((aligned(16))) bf16  pool_s[64 * 58];    // stride 58

    const int t    = threadIdx.x;
    const int lane = t & 63;
    const int wv   = t >> 6;
    const int img  = blockIdx.x >> 2;
    const int rb   = blockIdx.x & 3;
    const int pr0  = rb * 4;
    const int nt   = wv & 1;        // cout half this wave computes
    const int wp   = wv >> 1;       // Mt parity this wave computes

    const float* xi = x + img * 784;

    // conv1 weights into regs
    const int ci = t & 31;
    const int g  = t >> 5;          // g<7 active in conv1
    float w1r[9];
    #pragma unroll
    for (int k = 0; k < 9; k++) w1r[k] = W1[ci * 9 + k];
    const float b1r = b1[ci];

    // stage x tile: xs[j][c] = x[2*pr0-2+j][c-1]
    for (int e = t; e < 12 * 32; e += 256) {
        int j  = e >> 5;
        int c  = e & 31;
        int xr = 2 * pr0 - 2 + j;
        int xc = c - 1;
        float v = 0.f;
        if (xr >= 0 && xr < 28 && xc >= 0 && xc < 28) v = xi[xr * 28 + xc];
        xs[e] = v;
    }
    // zero halo cols 0 and 29 (rows fully written by conv1 below)
    for (int e = t; e < 640; e += 256) {
        int cz  = e & 31;
        int idx = e >> 5;           // 0..19
        int r   = idx >> 1;
        int p   = r * 30 + (idx & 1) * 29;
        h1s[(p * 32 + cz) ^ ((p & 6) << 2)] = (bf16)0.f;
    }
    __syncthreads();

    // W2 B-frags -> 72 VGPRs (L2-resident; latency hides behind conv1)
    bf16x8 breg[18];
    {
        const bf16x8* wp2 = (const bf16x8*)w2r;
        #pragma unroll
        for (int s = 0; s < 18; s++)
            breg[s] = wp2[(2 * s + nt) * 64 + lane];
    }

    // ---- conv1: register sliding window, 4-col strip per thread; always-write
    if (g < 7) {
        const int c0 = g * 4;
        float win[3][6];
        #pragma unroll
        for (int j0 = 0; j0 < 2; j0++) {
            f32x4 v = *(const f32x4*)&xs[j0 * 32 + c0];
            win[j0][0] = v[0]; win[j0][1] = v[1]; win[j0][2] = v[2]; win[j0][3] = v[3];
            win[j0][4] = xs[j0 * 32 + c0 + 4];
            win[j0][5] = xs[j0 * 32 + c0 + 5];
        }
        #pragma unroll
        for (int r = 0; r < 10; r++) {
            {
                float* d = win[(r + 2) % 3];
                f32x4 v = *(const f32x4*)&xs[(r + 2) * 32 + c0];
                d[0] = v[0]; d[1] = v[1]; d[2] = v[2]; d[3] = v[3];
                d[4] = xs[(r + 2) * 32 + c0 + 4];
                d[5] = xs[(r + 2) * 32 + c0 + 5];
            }
            int ghr = 2 * pr0 - 1 + r;
            bool rv = (ghr >= 0) && (ghr <= 27);
            const float* a0 = win[r % 3];
            const float* a1 = win[(r + 1) % 3];
            const float* a2 = win[(r + 2) % 3];
            #pragma unroll
            for (int j = 0; j < 4; j++) {
                float s = b1r
                    + a0[j] * w1r[0] + a0[j + 1] * w1r[1] + a0[j + 2] * w1r[2]
                    + a1[j] * w1r[3] + a1[j + 1] * w1r[4] + a1[j + 2] * w1r[5]
                    + a2[j] * w1r[6] + a2[j + 1] * w1r[7] + a2[j + 2] * w1r[8];
                float cm = a1[j + 1];
                float o  = (rv && cm != 0.f && s > 0.f) ? s : 0.f;
                int p = r * 30 + c0 + j + 1;
                h1s[(p * 32 + ci) ^ ((p & 6) << 2)] = (bf16)o;
            }
        }
    }
    __syncthreads();    // h1s ready

    // ---- conv2: per-Mt loop (32 M-rows = 8 pooled sites), MFMA 32x32x16
    const int ml31  = lane & 31;
    const int cib   = (lane >> 5) * 8;
    const int coutl = nt * 32 + ml31;
    const float bias = b2[coutl];
    const int nMt = (rb < 3) ? 7 : 4;
    const int nS  = (rb < 3) ? 56 : 28;

    for (int Mt = wp; Mt < nMt; Mt += 2) {
        // A-row address for this lane
        int m    = Mt * 32 + ml31;
        int site = m >> 2;
        if (site > nS - 1) site = nS - 1;       // rb=3 pad clamp
        int q  = m & 3;
        int pi = site / 14;
        int pj = site - pi * 14;
        int pb = (2 * pi + (q >> 1)) * 30 + 2 * pj + (q & 1);

        f32x16 acc = {};
        #pragma unroll
        for (int kt = 0; kt < 9; kt++) {
            const int dp = (kt / 3) * 30 + (kt % 3);
            int p  = pb + dp;
            int sw = (p & 6) << 2;
            int bs = p * 32;
            bf16x8 a0 = *(const bf16x8*)&h1s[(bs + cib) ^ sw];
            bf16x8 a1 = *(const bf16x8*)&h1s[(bs + 16 + cib) ^ sw];
            acc = __builtin_amdgcn_mfma_f32_32x32x16_bf16(a0, breg[2 * kt],     acc, 0, 0, 0);
            acc = __builtin_amdgcn_mfma_f32_32x32x16_bf16(a1, breg[2 * kt + 1], acc, 0, 0, 0);
        }
        // epilogue: each lane holds 4 complete pooled quads (g-groups)
        #pragma unroll
        for (int gg = 0; gg < 4; gg++) {
            int sl = 8 * Mt + 2 * gg + (lane >> 5);
            if (sl < nS) {
                int spi = sl / 14;
                int spj = sl - spi * 14;
                float pmax = 0.f;
                #pragma unroll
                for (int qi = 0; qi < 4; qi++) {
                    float v  = acc[gg * 4 + qi] + bias;
                    int y    = 2 * spi + (qi >> 1);
                    int xx   = 2 * spj + (qi & 1);
                    float cm = xs[(y + 2) * 32 + xx + 1];
                    v = (cm != 0.f && v > 0.f) ? v : 0.f;
                    pmax = v > pmax ? v : pmax;
                }
                pool_s[coutl * 58 + sl] = (bf16)pmax;
            }
        }
    }
    __syncthreads();

    // coalesced write-out (dwords): pooled[img][cout*196 + rb*56 + site]
    {
        const unsigned int* ps = (const unsigned int*)pool_s;
        unsigned int* op = (unsigned int*)pooled;
        if (rb < 3) {
            for (int e = t; e < 64 * 28; e += 256) {
                int cout = e / 28;
                int wd   = e - cout * 28;
                op[img * 6272 + cout * 98 + rb * 28 + wd] = ps[cout * 29 + wd];
            }
        } else {
            for (int e = t; e < 64 * 14; e += 256) {
                int cout = e / 14;
                int wd   = e - cout * 14;
                op[img * 6272 + cout * 98 + 84 + wd] = ps[cout * 29 + wd];
            }
        }
    }
}

// ---------------------------------------------------------------------------
// fc1: bf16 MFMA split-K GEMM, ping-pong double-buffered global_load_lds.
// part[ks][m][n] = A[m, ks*1568:+1568] * Wl1.  A = pooled bf16 [4096][12544];
// B = wl1t bf16 [128][12544]. grid (128 Mb x 8 Ks) = 1024 blocks, M-tile 32.
// Wave w: wm=w&1 (16 rows), wn=w>>1 (64 cols).
// ---------------------------------------------------------------------------
__global__ __launch_bounds__(256, 4)
void fc1(const bf16* __restrict__ pooled, const bf16* __restrict__ wl1t,
         float* __restrict__ part)
{
    __shared__ __attribute__((aligned(16))) bf16 As[2][32 * 32];
    __shared__ __attribute__((aligned(16))) bf16 Bs[2][128 * 32];

    const int t    = threadIdx.x;
    const int lane = t & 63;
    const int wv   = t >> 6;
    const int ml   = lane & 15;
    const int kg   = lane >> 4;
    const int wm   = wv & 1;
    const int wn   = wv >> 1;
    const int m0   = blockIdx.x * 32;
    const int ks   = blockIdx.y;
    const int k0   = ks * 1568;

    // A staging: waves 0,1 -> 64 chunks each (chunk = row quarter, swizzled src)
    const int achunk = wv * 64 + lane;          // 0..127 (wv<2)
    const int arow   = achunk >> 2;
    const int aqs    = (achunk & 3) ^ ((arow >> 1) & 3);
    const bf16* asrc = pooled + (long)(m0 + arow) * 12544 + aqs * 8;
    // B staging: all waves, 2 chunks (u=0,1)
    int bn[2], bofs[2];
    const bf16* bsrc[2];
    #pragma unroll
    for (int u = 0; u < 2; u++) {
        int c   = wv * 128 + u * 64 + lane;
        bn[u]   = c >> 2;
        int qs  = (c & 3) ^ ((bn[u] >> 1) & 3);
        bsrc[u] = wl1t + (long)bn[u] * 12544 + qs * 8;
        bofs[u] = (wv * 128 + u * 64) * 8;      // element base (wave-uniform)
    }

    // fragment offsets (per buffer)
    const int am  = wm * 16 + ml;
    const int aoff = (am * 32 + kg * 8) ^ ((am & 6) << 2);
    int boff[4];
    #pragma unroll
    for (int j = 0; j < 4; j++) {
        int n = wn * 64 + j * 16 + ml;
        boff[j] = (n * 32 + kg * 8) ^ ((n & 6) << 2);
    }

    f32x4 acc[4];
    {
        f32x4 z = {0.f, 0.f, 0.f, 0.f};
        #pragma unroll
        for (int j = 0; j < 4; j++) acc[j] = z;
    }

    // prologue: stage kt=0 into buf 0
    if (wv < 2) load_lds16(asrc + k0, &As[0][wv * 512]);
    #pragma unroll
    for (int u = 0; u < 2; u++) load_lds16(bsrc[u] + k0, &Bs[0][bofs[u]]);

    for (int kt = 0; kt < 49; kt++) {
        __syncthreads();                        // buf[cur] staged; buf[nxt] free
        const int cur = kt & 1;
        if (kt < 48) {                          // prefetch next tile (overlaps MFMA)
            const int kb = k0 + (kt + 1) * 32;
            const int nb = cur ^ 1;
            if (wv < 2) load_lds16(asrc + kb, &As[nb][wv * 512]);
            #pragma unroll
            for (int u = 0; u < 2; u++) load_lds16(bsrc[u] + kb, &Bs[nb][bofs[u]]);
        }
        bf16x8 af = *(const bf16x8*)&As[cur][aoff];
        #pragma unroll
        for (int j = 0; j < 4; j++) {
            bf16x8 bf = *(const bf16x8*)&Bs[cur][boff[j]];
            acc[j] = __builtin_amdgcn_mfma_f32_16x16x32_bf16(af, bf, acc[j], 0, 0, 0);
        }
    }

    float* pp = part + ((long)ks * 4096 + m0 + wm * 16) * 128 + wn * 64;
    #pragma unroll
    for (int j = 0; j < 4; j++)
        #pragma unroll
        for (int r = 0; r < 4; r++)
            pp[(kg * 4 + r) * 128 + j * 16 + ml] = acc[j][r];
}

// ---------------------------------------------------------------------------
// fc2_lsm: one wave per image; 8-way split-K reduce + FC2 + log_softmax.
// ---------------------------------------------------------------------------
__global__ __launch_bounds__(256)
void fc2_lsm(const float* __restrict__ part, const float* __restrict__ bl1,
             const float* __restrict__ Wl2, const float* __restrict__ bl2,
             float* __restrict__ out)
{
    const int wv   = threadIdx.x >> 6;
    const int lane = threadIdx.x & 63;
    const int img  = blockIdx.x * 4 + wv;
    const float* pb = part + (long)img * 128;

    float ac[10];
    #pragma unroll
    for (int c = 0; c < 10; c++) ac[c] = 0.f;

    #pragma unroll
    for (int u = 0; u < 2; u++) {
        int n = lane + 64 * u;
        float s = bl1[n];
        #pragma unroll
        for (int k = 0; k < 8; k++) s += pb[(long)k * 4096 * 128 + n];
        float h = s > 0.f ? s : 0.f;
        #pragma unroll
        for (int c = 0; c < 10; c++) ac[c] += h * Wl2[n * 10 + c];
    }
    #pragma unroll
    for (int o = 32; o > 0; o >>= 1)
        #pragma unroll
        for (int c = 0; c < 10; c++) ac[c] += __shfl_down(ac[c], o, 64);

    if (lane == 0) {
        float lg[10], mx = -1e30f;
        #pragma unroll
        for (int c = 0; c < 10; c++) {
            lg[c] = ac[c] + bl2[c];
            mx = lg[c] > mx ? lg[c] : mx;
        }
        float se = 0.f;
        #pragma unroll
        for (int c = 0; c < 10; c++) se += __expf(lg[c] - mx);
        float ls = __logf(se);
        #pragma unroll
        for (int c = 0; c < 10; c++) out[img * 10 + c] = lg[c] - mx - ls;
    }
}

// ---------------------------------------------------------------------------
extern "C" void kernel_launch(void* const* d_in, const int* in_sizes, int n_in,
                              void* d_out, int out_size, void* d_ws, size_t ws_size,
                              hipStream_t stream) {
    const float* x   = (const float*)d_in[0];
    const float* W1  = (const float*)d_in[1];
    const float* b1  = (const float*)d_in[2];
    const float* W2  = (const float*)d_in[3];
    const float* b2  = (const float*)d_in[4];
    const float* Wl1 = (const float*)d_in[5];
    const float* bl1 = (const float*)d_in[6];
    const float* Wl2 = (const float*)d_in[7];
    const float* bl2 = (const float*)d_in[8];
    float* out = (float*)d_out;

    char* ws = (char*)d_ws;
    bf16*  w2r    = (bf16*)ws;                                   // 36,864 B
    bf16*  wl1t   = (bf16*)(ws + 65536);                         // 3,211,264 B
    bf16*  pooled = (bf16*)(ws + 65536 + 4194304);               // 102,760,448 B
    float* part   = (float*)(ws + 65536 + 4194304 + 102760448);  // 16,777,216 B

    prep_w2   <<<72,             256, 0, stream>>>(W2, w2r);
    prep_wl1t <<<dim3(49, 128),  256, 0, stream>>>(Wl1, wl1t);
    conv_fused<<<16384,          256, 0, stream>>>(x, W1, b1, w2r, b2, pooled);
    fc1       <<<dim3(128, 8),   256, 0, stream>>>(pooled, wl1t, part);
    fc2_lsm   <<<1024,           256, 0, stream>>>(part, bl1, Wl2, bl2, out);
}

// Round 4
// 383.075 us; speedup vs baseline: 1.2177x; 1.2177x over previous
//
#include <hip/hip_runtime.h>
#include <math.h>

typedef __bf16 bf16;
typedef __bf16 bf16x8 __attribute__((ext_vector_type(8)));
typedef float f32x4 __attribute__((ext_vector_type(4)));
typedef float f32x16 __attribute__((ext_vector_type(16)));
typedef unsigned int u32x4 __attribute__((ext_vector_type(4)));

__device__ __forceinline__ void load_lds16(const void* g, void* l) {
    __builtin_amdgcn_global_load_lds(
        (const __attribute__((address_space(1))) unsigned int*)g,
        (__attribute__((address_space(3))) unsigned int*)l, 16, 0, 0);
}

// ---------------------------------------------------------------------------
// prep_w2: W2 [cout][ci][tap] f32 -> B-fragment buffer for mfma_32x32x16_bf16.
// frag f = s*2 + nt  (s = K-slice 0..17: tap=s>>1, ci_base=(s&1)*16; nt = cout half)
// w2r[(f*64 + lane)*8 + j] = W2[cout = nt*32+(lane&31)][ci = ci_base+(lane>>5)*8+j][tap]
// ---------------------------------------------------------------------------
__global__ void prep_w2(const float* __restrict__ W2, bf16* __restrict__ w2r) {
    int e = blockIdx.x * 256 + threadIdx.x;     // 0..18431
    int j  = e & 7;
    int l  = (e >> 3) & 63;
    int f  = e >> 9;
    int s  = f >> 1;
    int nt = f & 1;
    int tap  = s >> 1;
    int ci   = (s & 1) * 16 + (l >> 5) * 8 + j;
    int cout = nt * 32 + (l & 31);
    w2r[e] = (bf16)W2[cout * 288 + ci * 9 + tap];
}

// ---------------------------------------------------------------------------
// prep_wl1t: Wl1 f32 [12544][128] -> bf16 transposed [128][12544].
// 32x32 LDS-tiled transpose, coalesced on both global sides.
// ---------------------------------------------------------------------------
__global__ void prep_wl1t(const float* __restrict__ Wl1, bf16* __restrict__ wl1t) {
    __shared__ float tile[32][33];
    const int tx = threadIdx.x & 31;
    const int ty = threadIdx.x >> 5;            // 0..7
    const int k0 = blockIdx.x * 32;
    const int n0 = blockIdx.y * 32;
    #pragma unroll
    for (int i = 0; i < 4; i++)
        tile[ty + i * 8][tx] = Wl1[(long)(k0 + ty + i * 8) * 128 + n0 + tx];
    __syncthreads();
    #pragma unroll
    for (int i = 0; i < 4; i++)
        wl1t[(long)(n0 + ty + i * 8) * 12544 + k0 + tx] = (bf16)tile[tx][ty + i * 8];
}

// ---------------------------------------------------------------------------
// conv_fused: conv1(masked,relu,VALU) + conv2(masked,relu,MFMA 32x32x16) + pool.
// One block = one image * 4 pooled rows. W2 B-frags live in 72 VGPRs per wave
// (nt = wv&1 selects 32 couts). launch_bounds(256,3): 170-VGPR cap -> NO SPILL
// (R3 lesson: (256,4) capped at 64 VGPR and spilled breg -> 870 MB scratch).
// ---------------------------------------------------------------------------
__global__ __launch_bounds__(256, 3)
void conv_fused(const float* __restrict__ x, const float* __restrict__ W1,
                const float* __restrict__ b1, const bf16* __restrict__ w2r,
                const float* __restrict__ b2, bf16* __restrict__ pooled)
{
    __shared__ __attribute__((aligned(16))) bf16  h1s[10 * 30 * 32];  // swizzled
    __shared__ __attribute__((aligned(16))) float xs[12 * 32];
    __shared__ __attribute__((aligned(16))) bf16  pool_s[64 * 58];    // stride 58

    const int t    = threadIdx.x;
    const int lane = t & 63;
    const int wv   = t >> 6;
    const int img  = blockIdx.x >> 2;
    const int rb   = blockIdx.x & 3;
    const int pr0  = rb * 4;
    const int nt   = wv & 1;        // cout half this wave computes
    const int wp   = wv >> 1;       // Mt parity this wave computes

    const float* xi = x + img * 784;

    // W2 B-frags -> 72 VGPRs early (L2-resident; latency hides behind staging)
    bf16x8 breg[18];
    {
        const bf16x8* wp2 = (const bf16x8*)w2r;
        #pragma unroll
        for (int s = 0; s < 18; s++)
            breg[s] = wp2[(2 * s + nt) * 64 + lane];
    }

    // conv1 weights into regs
    const int ci = t & 31;
    const int g  = t >> 5;          // g<7 active in conv1
    float w1r[9];
    #pragma unroll
    for (int k = 0; k < 9; k++) w1r[k] = W1[ci * 9 + k];
    const float b1r = b1[ci];

    // stage x tile: xs[j][c] = x[2*pr0-2+j][c-1]
    for (int e = t; e < 12 * 32; e += 256) {
        int j  = e >> 5;
        int c  = e & 31;
        int xr = 2 * pr0 - 2 + j;
        int xc = c - 1;
        float v = 0.f;
        if (xr >= 0 && xr < 28 && xc >= 0 && xc < 28) v = xi[xr * 28 + xc];
        xs[e] = v;
    }
    // zero halo cols 0 and 29 (rows fully written by conv1 below)
    for (int e = t; e < 640; e += 256) {
        int cz  = e & 31;
        int idx = e >> 5;           // 0..19
        int r   = idx >> 1;
        int p   = r * 30 + (idx & 1) * 29;
        h1s[(p * 32 + cz) ^ ((p & 6) << 2)] = (bf16)0.f;
    }
    __syncthreads();

    // ---- conv1: register sliding window, 4-col strip per thread; always-write
    if (g < 7) {
        const int c0 = g * 4;
        float win[3][6];
        #pragma unroll
        for (int j0 = 0; j0 < 2; j0++) {
            f32x4 v = *(const f32x4*)&xs[j0 * 32 + c0];
            win[j0][0] = v[0]; win[j0][1] = v[1]; win[j0][2] = v[2]; win[j0][3] = v[3];
            win[j0][4] = xs[j0 * 32 + c0 + 4];
            win[j0][5] = xs[j0 * 32 + c0 + 5];
        }
        #pragma unroll
        for (int r = 0; r < 10; r++) {
            {
                float* d = win[(r + 2) % 3];
                f32x4 v = *(const f32x4*)&xs[(r + 2) * 32 + c0];
                d[0] = v[0]; d[1] = v[1]; d[2] = v[2]; d[3] = v[3];
                d[4] = xs[(r + 2) * 32 + c0 + 4];
                d[5] = xs[(r + 2) * 32 + c0 + 5];
            }
            int ghr = 2 * pr0 - 1 + r;
            bool rv = (ghr >= 0) && (ghr <= 27);
            const float* a0 = win[r % 3];
            const float* a1 = win[(r + 1) % 3];
            const float* a2 = win[(r + 2) % 3];
            #pragma unroll
            for (int j = 0; j < 4; j++) {
                float s = b1r
                    + a0[j] * w1r[0] + a0[j + 1] * w1r[1] + a0[j + 2] * w1r[2]
                    + a1[j] * w1r[3] + a1[j + 1] * w1r[4] + a1[j + 2] * w1r[5]
                    + a2[j] * w1r[6] + a2[j + 1] * w1r[7] + a2[j + 2] * w1r[8];
                float cm = a1[j + 1];
                float o  = (rv && cm != 0.f && s > 0.f) ? s : 0.f;
                int p = r * 30 + c0 + j + 1;
                h1s[(p * 32 + ci) ^ ((p & 6) << 2)] = (bf16)o;
            }
        }
    }
    __syncthreads();    // h1s ready

    // ---- conv2: per-Mt loop (32 M-rows = 8 pooled sites), MFMA 32x32x16
    const int ml31  = lane & 31;
    const int cib   = (lane >> 5) * 8;
    const int coutl = nt * 32 + ml31;
    const float bias = b2[coutl];
    const int nMt = (rb < 3) ? 7 : 4;
    const int nS  = (rb < 3) ? 56 : 28;

    for (int Mt = wp; Mt < nMt; Mt += 2) {
        // A-row address for this lane
        int m    = Mt * 32 + ml31;
        int site = m >> 2;
        if (site > nS - 1) site = nS - 1;       // rb=3 pad clamp
        int q  = m & 3;
        int pi = site / 14;
        int pj = site - pi * 14;
        int pb = (2 * pi + (q >> 1)) * 30 + 2 * pj + (q & 1);

        f32x16 acc = {};
        #pragma unroll
        for (int kt = 0; kt < 9; kt++) {
            const int dp = (kt / 3) * 30 + (kt % 3);
            int p  = pb + dp;
            int sw = (p & 6) << 2;
            int bs = p * 32;
            bf16x8 a0 = *(const bf16x8*)&h1s[(bs + cib) ^ sw];
            bf16x8 a1 = *(const bf16x8*)&h1s[(bs + 16 + cib) ^ sw];
            acc = __builtin_amdgcn_mfma_f32_32x32x16_bf16(a0, breg[2 * kt],     acc, 0, 0, 0);
            acc = __builtin_amdgcn_mfma_f32_32x32x16_bf16(a1, breg[2 * kt + 1], acc, 0, 0, 0);
        }
        // epilogue: each lane holds 4 complete pooled quads (g-groups)
        #pragma unroll
        for (int gg = 0; gg < 4; gg++) {
            int sl = 8 * Mt + 2 * gg + (lane >> 5);
            if (sl < nS) {
                int spi = sl / 14;
                int spj = sl - spi * 14;
                float pmax = 0.f;
                #pragma unroll
                for (int qi = 0; qi < 4; qi++) {
                    float v  = acc[gg * 4 + qi] + bias;
                    int y    = 2 * spi + (qi >> 1);
                    int xx   = 2 * spj + (qi & 1);
                    float cm = xs[(y + 2) * 32 + xx + 1];
                    v = (cm != 0.f && v > 0.f) ? v : 0.f;
                    pmax = v > pmax ? v : pmax;
                }
                pool_s[coutl * 58 + sl] = (bf16)pmax;
            }
        }
    }
    __syncthreads();

    // coalesced write-out (dwords): pooled[img][cout*196 + rb*56 + site]
    {
        const unsigned int* ps = (const unsigned int*)pool_s;
        unsigned int* op = (unsigned int*)pooled;
        if (rb < 3) {
            for (int e = t; e < 64 * 28; e += 256) {
                int cout = e / 28;
                int wd   = e - cout * 28;
                op[img * 6272 + cout * 98 + rb * 28 + wd] = ps[cout * 29 + wd];
            }
        } else {
            for (int e = t; e < 64 * 14; e += 256) {
                int cout = e / 14;
                int wd   = e - cout * 14;
                op[img * 6272 + cout * 98 + 84 + wd] = ps[cout * 29 + wd];
            }
        }
    }
}

// ---------------------------------------------------------------------------
// fc1: bf16 MFMA split-K GEMM, ping-pong double-buffered global_load_lds.
// part[ks][m][n] = A[m, ks*1568:+1568] * Wl1.  A = pooled bf16 [4096][12544];
// B = wl1t bf16 [128][12544]. grid (128 Mb x 8 Ks) = 1024 blocks, M-tile 32.
// ---------------------------------------------------------------------------
__global__ __launch_bounds__(256, 4)
void fc1(const bf16* __restrict__ pooled, const bf16* __restrict__ wl1t,
         float* __restrict__ part)
{
    __shared__ __attribute__((aligned(16))) bf16 As[2][32 * 32];
    __shared__ __attribute__((aligned(16))) bf16 Bs[2][128 * 32];

    const int t    = threadIdx.x;
    const int lane = t & 63;
    const int wv   = t >> 6;
    const int ml   = lane & 15;
    const int kg   = lane >> 4;
    const int wm   = wv & 1;
    const int wn   = wv >> 1;
    const int m0   = blockIdx.x * 32;
    const int ks   = blockIdx.y;
    const int k0   = ks * 1568;

    const int achunk = wv * 64 + lane;          // 0..127 (wv<2)
    const int arow   = achunk >> 2;
    const int aqs    = (achunk & 3) ^ ((arow >> 1) & 3);
    const bf16* asrc = pooled + (long)(m0 + arow) * 12544 + aqs * 8;

    int bn[2], bofs[2];
    const bf16* bsrc[2];
    #pragma unroll
    for (int u = 0; u < 2; u++) {
        int c   = wv * 128 + u * 64 + lane;
        bn[u]   = c >> 2;
        int qs  = (c & 3) ^ ((bn[u] >> 1) & 3);
        bsrc[u] = wl1t + (long)bn[u] * 12544 + qs * 8;
        bofs[u] = (wv * 128 + u * 64) * 8;
    }

    const int am  = wm * 16 + ml;
    const int aoff = (am * 32 + kg * 8) ^ ((am & 6) << 2);
    int boff[4];
    #pragma unroll
    for (int j = 0; j < 4; j++) {
        int n = wn * 64 + j * 16 + ml;
        boff[j] = (n * 32 + kg * 8) ^ ((n & 6) << 2);
    }

    f32x4 acc[4];
    {
        f32x4 z = {0.f, 0.f, 0.f, 0.f};
        #pragma unroll
        for (int j = 0; j < 4; j++) acc[j] = z;
    }

    if (wv < 2) load_lds16(asrc + k0, &As[0][wv * 512]);
    #pragma unroll
    for (int u = 0; u < 2; u++) load_lds16(bsrc[u] + k0, &Bs[0][bofs[u]]);

    for (int kt = 0; kt < 49; kt++) {
        __syncthreads();
        const int cur = kt & 1;
        if (kt < 48) {
            const int kb = k0 + (kt + 1) * 32;
            const int nb = cur ^ 1;
            if (wv < 2) load_lds16(asrc + kb, &As[nb][wv * 512]);
            #pragma unroll
            for (int u = 0; u < 2; u++) load_lds16(bsrc[u] + kb, &Bs[nb][bofs[u]]);
        }
        bf16x8 af = *(const bf16x8*)&As[cur][aoff];
        #pragma unroll
        for (int j = 0; j < 4; j++) {
            bf16x8 bf = *(const bf16x8*)&Bs[cur][boff[j]];
            acc[j] = __builtin_amdgcn_mfma_f32_16x16x32_bf16(af, bf, acc[j], 0, 0, 0);
        }
    }

    float* pp = part + ((long)ks * 4096 + m0 + wm * 16) * 128 + wn * 64;
    #pragma unroll
    for (int j = 0; j < 4; j++)
        #pragma unroll
        for (int r = 0; r < 4; r++)
            pp[(kg * 4 + r) * 128 + j * 16 + ml] = acc[j][r];
}

// ---------------------------------------------------------------------------
// fc2_lsm: one wave per image; 8-way split-K reduce + FC2 + log_softmax.
// ---------------------------------------------------------------------------
__global__ __launch_bounds__(256)
void fc2_lsm(const float* __restrict__ part, const float* __restrict__ bl1,
             const float* __restrict__ Wl2, const float* __restrict__ bl2,
             float* __restrict__ out)
{
    const int wv   = threadIdx.x >> 6;
    const int lane = threadIdx.x & 63;
    const int img  = blockIdx.x * 4 + wv;
    const float* pb = part + (long)img * 128;

    float ac[10];
    #pragma unroll
    for (int c = 0; c < 10; c++) ac[c] = 0.f;

    #pragma unroll
    for (int u = 0; u < 2; u++) {
        int n = lane + 64 * u;
        float s = bl1[n];
        #pragma unroll
        for (int k = 0; k < 8; k++) s += pb[(long)k * 4096 * 128 + n];
        float h = s > 0.f ? s : 0.f;
        #pragma unroll
        for (int c = 0; c < 10; c++) ac[c] += h * Wl2[n * 10 + c];
    }
    #pragma unroll
    for (int o = 32; o > 0; o >>= 1)
        #pragma unroll
        for (int c = 0; c < 10; c++) ac[c] += __shfl_down(ac[c], o, 64);

    if (lane == 0) {
        float lg[10], mx = -1e30f;
        #pragma unroll
        for (int c = 0; c < 10; c++) {
            lg[c] = ac[c] + bl2[c];
            mx = lg[c] > mx ? lg[c] : mx;
        }
        float se = 0.f;
        #pragma unroll
        for (int c = 0; c < 10; c++) se += __expf(lg[c] - mx);
        float ls = __logf(se);
        #pragma unroll
        for (int c = 0; c < 10; c++) out[img * 10 + c] = lg[c] - mx - ls;
    }
}

// ---------------------------------------------------------------------------
extern "C" void kernel_launch(void* const* d_in, const int* in_sizes, int n_in,
                              void* d_out, int out_size, void* d_ws, size_t ws_size,
                              hipStream_t stream) {
    const float* x   = (const float*)d_in[0];
    const float* W1  = (const float*)d_in[1];
    const float* b1  = (const float*)d_in[2];
    const float* W2  = (const float*)d_in[3];
    const float* b2  = (const float*)d_in[4];
    const float* Wl1 = (const float*)d_in[5];
    const float* bl1 = (const float*)d_in[6];
    const float* Wl2 = (const float*)d_in[7];
    const float* bl2 = (const float*)d_in[8];
    float* out = (float*)d_out;

    char* ws = (char*)d_ws;
    bf16*  w2r    = (bf16*)ws;                                   // 36,864 B
    bf16*  wl1t   = (bf16*)(ws + 65536);                         // 3,211,264 B
    bf16*  pooled = (bf16*)(ws + 65536 + 4194304);               // 102,760,448 B
    float* part   = (float*)(ws + 65536 + 4194304 + 102760448);  // 16,777,216 B

    prep_w2   <<<72,             256, 0, stream>>>(W2, w2r);
    prep_wl1t <<<dim3(392, 4),   256, 0, stream>>>(Wl1, wl1t);
    conv_fused<<<16384,          256, 0, stream>>>(x, W1, b1, w2r, b2, pooled);
    fc1       <<<dim3(128, 8),   256, 0, stream>>>(pooled, wl1t, part);
    fc2_lsm   <<<1024,           256, 0, stream>>>(part, bl1, Wl2, bl2, out);
}

// Round 5
// 336.108 us; speedup vs baseline: 1.3879x; 1.1397x over previous
//
#include <hip/hip_runtime.h>
#include <math.h>

typedef __bf16 bf16;
typedef __bf16 bf16x8 __attribute__((ext_vector_type(8)));
typedef float f32x4 __attribute__((ext_vector_type(4)));
typedef float f32x16 __attribute__((ext_vector_type(16)));
typedef unsigned int u32x4 __attribute__((ext_vector_type(4)));

__device__ __forceinline__ void load_lds16(const void* g, void* l) {
    __builtin_amdgcn_global_load_lds(
        (const __attribute__((address_space(1))) unsigned int*)g,
        (__attribute__((address_space(3))) unsigned int*)l, 16, 0, 0);
}

// ---------------------------------------------------------------------------
// prep_w2: W2 [cout][ci][tap] f32 -> B-fragment buffer for mfma_32x32x16_bf16.
// frag f = s*2 + nt  (s = K-slice 0..17: tap=s>>1, ci_base=(s&1)*16; nt = cout half)
// ---------------------------------------------------------------------------
__global__ void prep_w2(const float* __restrict__ W2, bf16* __restrict__ w2r) {
    int e = blockIdx.x * 256 + threadIdx.x;     // 0..18431
    int j  = e & 7;
    int l  = (e >> 3) & 63;
    int f  = e >> 9;
    int s  = f >> 1;
    int nt = f & 1;
    int tap  = s >> 1;
    int ci   = (s & 1) * 16 + (l >> 5) * 8 + j;
    int cout = nt * 32 + (l & 31);
    w2r[e] = (bf16)W2[cout * 288 + ci * 9 + tap];
}

// ---------------------------------------------------------------------------
// prep_wl1t: Wl1 f32 [12544][128] -> bf16 [128][12544] with permuted K:
// wl1t[n][k'] where k' = site*64 + cout  <->  Wl1 row k = cout*196 + site.
// Matches conv epilogue's direct [img][site][cout] pooled layout.
// Block = (site, cout-half 32); LDS 32x(128+1) f32 transpose tile.
// ---------------------------------------------------------------------------
__global__ void prep_wl1t(const float* __restrict__ Wl1, bf16* __restrict__ wl1t) {
    __shared__ float tile[32 * 129];
    const int t  = threadIdx.x;
    const int s  = blockIdx.x;      // site 0..195
    const int cg = blockIdx.y;      // cout half
    for (int e = t; e < 4096; e += 256) {
        int cl = e >> 7, n = e & 127;
        tile[cl * 129 + n] = Wl1[((long)(cg * 32 + cl) * 196 + s) * 128 + n];
    }
    __syncthreads();
    for (int e = t; e < 4096; e += 256) {
        int n = e >> 5, cl = e & 31;
        wl1t[(long)n * 12544 + s * 64 + cg * 32 + cl] = (bf16)tile[cl * 129 + n];
    }
}

// ---------------------------------------------------------------------------
// conv_fused: conv1(masked,relu,VALU) + conv2(masked,relu,MFMA 32x32x16) + pool.
// One block = one image HALF (14 pooled rows? no: 7 pooled rows = 14 conv rows,
// h1 tile 16 rows x 30 cols x 32 ci). W2 B-frags in 72 VGPRs/wave.
// Epilogue stores pooled[img][site*64+cout] bf16 directly (64B/half-wave).
// launch_bounds(256,3): VGPR cap ~170, no spill (R3 lesson: (256,4) => spill).
// ---------------------------------------------------------------------------
__global__ __launch_bounds__(256, 3)
void conv_fused(const float* __restrict__ x, const float* __restrict__ W1,
                const float* __restrict__ b1, const bf16* __restrict__ w2r,
                const float* __restrict__ b2, bf16* __restrict__ pooled)
{
    __shared__ __attribute__((aligned(16))) bf16  h1s[16 * 30 * 32];  // swizzled
    __shared__ __attribute__((aligned(16))) float xs[18 * 32];

    const int t    = threadIdx.x;
    const int lane = t & 63;
    const int wv   = t >> 6;
    const int img  = blockIdx.x >> 1;
    const int hb   = blockIdx.x & 1;        // image half
    const int nt   = wv & 1;                // cout half this wave computes
    const int wp   = wv >> 1;               // Mt parity this wave computes

    const float* xi = x + img * 784;

    // W2 B-frags -> 72 VGPRs early (L2-resident; latency hides behind staging)
    bf16x8 breg[18];
    {
        const bf16x8* wp2 = (const bf16x8*)w2r;
        #pragma unroll
        for (int s = 0; s < 18; s++)
            breg[s] = wp2[(2 * s + nt) * 64 + lane];
    }

    // conv1 weights into regs
    const int ci = t & 31;
    const int g  = t >> 5;          // g<7 active in conv1
    float w1r[9];
    #pragma unroll
    for (int k = 0; k < 9; k++) w1r[k] = W1[ci * 9 + k];
    const float b1r = b1[ci];

    // stage x tile: xs[j][c] = x[hb*14-2+j][c-1], 18 rows
    for (int e = t; e < 18 * 32; e += 256) {
        int j  = e >> 5;
        int c  = e & 31;
        int xr = hb * 14 - 2 + j;
        int xc = c - 1;
        float v = 0.f;
        if (xr >= 0 && xr < 28 && xc >= 0 && xc < 28) v = xi[xr * 28 + xc];
        xs[e] = v;
    }
    // zero halo cols 0 and 29 (16 rows; swizzle permutes within-row dwords only)
    for (int e = t; e < 512; e += 256) {
        int d   = e & 15;
        int idx = e >> 4;           // 0..31
        int r   = idx >> 1;
        int p   = r * 30 + (idx & 1) * 29;
        ((unsigned int*)h1s)[p * 16 + d] = 0u;
    }
    __syncthreads();

    // ---- conv1: register sliding window, 4-col strip per thread; always-write
    if (g < 7) {
        const int c0 = g * 4;
        float win[3][6];
        #pragma unroll
        for (int j0 = 0; j0 < 2; j0++) {
            f32x4 v = *(const f32x4*)&xs[j0 * 32 + c0];
            win[j0][0] = v[0]; win[j0][1] = v[1]; win[j0][2] = v[2]; win[j0][3] = v[3];
            win[j0][4] = xs[j0 * 32 + c0 + 4];
            win[j0][5] = xs[j0 * 32 + c0 + 5];
        }
        #pragma unroll
        for (int r = 0; r < 16; r++) {
            {
                float* d = win[(r + 2) % 3];
                f32x4 v = *(const f32x4*)&xs[(r + 2) * 32 + c0];
                d[0] = v[0]; d[1] = v[1]; d[2] = v[2]; d[3] = v[3];
                d[4] = xs[(r + 2) * 32 + c0 + 4];
                d[5] = xs[(r + 2) * 32 + c0 + 5];
            }
            int ghr = hb * 14 - 1 + r;          // global conv row
            bool rv = (ghr >= 0) && (ghr <= 27);
            const float* a0 = win[r % 3];
            const float* a1 = win[(r + 1) % 3];
            const float* a2 = win[(r + 2) % 3];
            #pragma unroll
            for (int j = 0; j < 4; j++) {
                float s = b1r
                    + a0[j] * w1r[0] + a0[j + 1] * w1r[1] + a0[j + 2] * w1r[2]
                    + a1[j] * w1r[3] + a1[j + 1] * w1r[4] + a1[j + 2] * w1r[5]
                    + a2[j] * w1r[6] + a2[j + 1] * w1r[7] + a2[j + 2] * w1r[8];
                float cm = a1[j + 1];
                float o  = (rv && cm != 0.f && s > 0.f) ? s : 0.f;
                int p = r * 30 + c0 + j + 1;
                h1s[(p * 32 + ci) ^ ((p & 6) << 2)] = (bf16)o;
            }
        }
    }
    __syncthreads();    // h1s ready

    // ---- conv2: Mt loop over 13 tiles of 32 M-rows (98 pooled sites/half)
    const int ml31  = lane & 31;
    const int half  = lane >> 5;
    const int cib   = half * 8;
    const int coutl = nt * 32 + ml31;
    const float bias = b2[coutl];

    // incremental (pi,pj) for A-addresses: site = Mt*8 + (ml31>>2), q = ml31&3
    int q  = ml31 & 3;
    int pj = wp * 8 + (ml31 >> 2);
    int pi = 0;
    if (pj >= 14) { pj -= 14; pi = 1; }
    // incremental epilogue site base: es = 8*Mt + half (gg adds 2)
    int epj = wp * 8 + half;
    int epi = 0;

    bf16* pout = pooled + (long)img * 12544 + hb * 98 * 64 + coutl;

    for (int Mt = wp; Mt < 13; Mt += 2) {
        int row = 2 * pi + (q >> 1);
        if (row > 13) row = 13;                 // Mt=12 tail clamp (stores guarded)
        int pb = row * 30 + 2 * pj + (q & 1);

        f32x16 acc = {};
        #pragma unroll
        for (int kt = 0; kt < 9; kt++) {
            const int dp = (kt / 3) * 30 + (kt % 3);
            int p  = pb + dp;
            int sw = (p & 6) << 2;
            int bs = p * 32;
            bf16x8 a0 = *(const bf16x8*)&h1s[(bs + cib) ^ sw];
            bf16x8 a1 = *(const bf16x8*)&h1s[(bs + 16 + cib) ^ sw];
            acc = __builtin_amdgcn_mfma_f32_32x32x16_bf16(a0, breg[2 * kt],     acc, 0, 0, 0);
            acc = __builtin_amdgcn_mfma_f32_32x32x16_bf16(a1, breg[2 * kt + 1], acc, 0, 0, 0);
        }

        // epilogue: +bias, mask, relu, 2x2 maxpool, direct global store
        int e_pi = epi, e_pj = epj;
        int slg  = 8 * Mt + half;
        #pragma unroll
        for (int gg = 0; gg < 4; gg++) {
            if (slg < 98) {
                float pmax = 0.f;
                #pragma unroll
                for (int qi = 0; qi < 4; qi++) {
                    float v  = acc[gg * 4 + qi] + bias;
                    float cm = xs[(2 * e_pi + (qi >> 1) + 2) * 32
                                  + 2 * e_pj + (qi & 1) + 1];
                    v = (cm != 0.f && v > 0.f) ? v : 0.f;
                    pmax = v > pmax ? v : pmax;
                }
                pout[slg * 64] = (bf16)pmax;
            }
            slg += 2;
            e_pj += 2; if (e_pj >= 14) { e_pj -= 14; e_pi += 1; }
        }

        // advance lane site by 16 (Mt += 2): pj += 2 (wrap), pi += 1
        pj += 2; if (pj >= 14) { pj -= 14; pi += 1; }
        pi += 1;
        epj += 2; if (epj >= 14) { epj -= 14; epi += 1; }
        epi += 1;
    }
}

// ---------------------------------------------------------------------------
// fc1: bf16 MFMA split-K GEMM, ping-pong double-buffered global_load_lds.
// part[ks][m][n] = A[m, ks*1568:+1568] * Wl1.  A = pooled bf16 [4096][12544];
// B = wl1t bf16 [128][12544] (same permuted K order). grid (128 Mb x 8 Ks).
// ---------------------------------------------------------------------------
__global__ __launch_bounds__(256, 4)
void fc1(const bf16* __restrict__ pooled, const bf16* __restrict__ wl1t,
         float* __restrict__ part)
{
    __shared__ __attribute__((aligned(16))) bf16 As[2][32 * 32];
    __shared__ __attribute__((aligned(16))) bf16 Bs[2][128 * 32];

    const int t    = threadIdx.x;
    const int lane = t & 63;
    const int wv   = t >> 6;
    const int ml   = lane & 15;
    const int kg   = lane >> 4;
    const int wm   = wv & 1;
    const int wn   = wv >> 1;
    const int m0   = blockIdx.x * 32;
    const int ks   = blockIdx.y;
    const int k0   = ks * 1568;

    const int achunk = wv * 64 + lane;          // 0..127 (wv<2)
    const int arow   = achunk >> 2;
    const int aqs    = (achunk & 3) ^ ((arow >> 1) & 3);
    const bf16* asrc = pooled + (long)(m0 + arow) * 12544 + aqs * 8;

    int bn[2], bofs[2];
    const bf16* bsrc[2];
    #pragma unroll
    for (int u = 0; u < 2; u++) {
        int c   = wv * 128 + u * 64 + lane;
        bn[u]   = c >> 2;
        int qs  = (c & 3) ^ ((bn[u] >> 1) & 3);
        bsrc[u] = wl1t + (long)bn[u] * 12544 + qs * 8;
        bofs[u] = (wv * 128 + u * 64) * 8;
    }

    const int am  = wm * 16 + ml;
    const int aoff = (am * 32 + kg * 8) ^ ((am & 6) << 2);
    int boff[4];
    #pragma unroll
    for (int j = 0; j < 4; j++) {
        int n = wn * 64 + j * 16 + ml;
        boff[j] = (n * 32 + kg * 8) ^ ((n & 6) << 2);
    }

    f32x4 acc[4];
    {
        f32x4 z = {0.f, 0.f, 0.f, 0.f};
        #pragma unroll
        for (int j = 0; j < 4; j++) acc[j] = z;
    }

    if (wv < 2) load_lds16(asrc + k0, &As[0][wv * 512]);
    #pragma unroll
    for (int u = 0; u < 2; u++) load_lds16(bsrc[u] + k0, &Bs[0][bofs[u]]);

    for (int kt = 0; kt < 49; kt++) {
        __syncthreads();
        const int cur = kt & 1;
        if (kt < 48) {
            const int kb = k0 + (kt + 1) * 32;
            const int nb = cur ^ 1;
            if (wv < 2) load_lds16(asrc + kb, &As[nb][wv * 512]);
            #pragma unroll
            for (int u = 0; u < 2; u++) load_lds16(bsrc[u] + kb, &Bs[nb][bofs[u]]);
        }
        bf16x8 af = *(const bf16x8*)&As[cur][aoff];
        #pragma unroll
        for (int j = 0; j < 4; j++) {
            bf16x8 bf = *(const bf16x8*)&Bs[cur][boff[j]];
            acc[j] = __builtin_amdgcn_mfma_f32_16x16x32_bf16(af, bf, acc[j], 0, 0, 0);
        }
    }

    float* pp = part + ((long)ks * 4096 + m0 + wm * 16) * 128 + wn * 64;
    #pragma unroll
    for (int j = 0; j < 4; j++)
        #pragma unroll
        for (int r = 0; r < 4; r++)
            pp[(kg * 4 + r) * 128 + j * 16 + ml] = acc[j][r];
}

// ---------------------------------------------------------------------------
// fc2_lsm: one wave per image; 8-way split-K reduce + FC2 + log_softmax.
// ---------------------------------------------------------------------------
__global__ __launch_bounds__(256)
void fc2_lsm(const float* __restrict__ part, const float* __restrict__ bl1,
             const float* __restrict__ Wl2, const float* __restrict__ bl2,
             float* __restrict__ out)
{
    const int wv   = threadIdx.x >> 6;
    const int lane = threadIdx.x & 63;
    const int img  = blockIdx.x * 4 + wv;
    const float* pb = part + (long)img * 128;

    float ac[10];
    #pragma unroll
    for (int c = 0; c < 10; c++) ac[c] = 0.f;

    #pragma unroll
    for (int u = 0; u < 2; u++) {
        int n = lane + 64 * u;
        float s = bl1[n];
        #pragma unroll
        for (int k = 0; k < 8; k++) s += pb[(long)k * 4096 * 128 + n];
        float h = s > 0.f ? s : 0.f;
        #pragma unroll
        for (int c = 0; c < 10; c++) ac[c] += h * Wl2[n * 10 + c];
    }
    #pragma unroll
    for (int o = 32; o > 0; o >>= 1)
        #pragma unroll
        for (int c = 0; c < 10; c++) ac[c] += __shfl_down(ac[c], o, 64);

    if (lane == 0) {
        float lg[10], mx = -1e30f;
        #pragma unroll
        for (int c = 0; c < 10; c++) {
            lg[c] = ac[c] + bl2[c];
            mx = lg[c] > mx ? lg[c] : mx;
        }
        float se = 0.f;
        #pragma unroll
        for (int c = 0; c < 10; c++) se += __expf(lg[c] - mx);
        float ls = __logf(se);
        #pragma unroll
        for (int c = 0; c < 10; c++) out[img * 10 + c] = lg[c] - mx - ls;
    }
}

// ---------------------------------------------------------------------------
extern "C" void kernel_launch(void* const* d_in, const int* in_sizes, int n_in,
                              void* d_out, int out_size, void* d_ws, size_t ws_size,
                              hipStream_t stream) {
    const float* x   = (const float*)d_in[0];
    const float* W1  = (const float*)d_in[1];
    const float* b1  = (const float*)d_in[2];
    const float* W2  = (const float*)d_in[3];
    const float* b2  = (const float*)d_in[4];
    const float* Wl1 = (const float*)d_in[5];
    const float* bl1 = (const float*)d_in[6];
    const float* Wl2 = (const float*)d_in[7];
    const float* bl2 = (const float*)d_in[8];
    float* out = (float*)d_out;

    char* ws = (char*)d_ws;
    bf16*  w2r    = (bf16*)ws;                                   // 36,864 B
    bf16*  wl1t   = (bf16*)(ws + 65536);                         // 3,211,264 B
    bf16*  pooled = (bf16*)(ws + 65536 + 4194304);               // 102,760,448 B
    float* part   = (float*)(ws + 65536 + 4194304 + 102760448);  // 16,777,216 B

    prep_w2   <<<72,             256, 0, stream>>>(W2, w2r);
    prep_wl1t <<<dim3(196, 2),   256, 0, stream>>>(Wl1, wl1t);
    conv_fused<<<8192,           256, 0, stream>>>(x, W1, b1, w2r, b2, pooled);
    fc1       <<<dim3(128, 8),   256, 0, stream>>>(pooled, wl1t, part);
    fc2_lsm   <<<1024,           256, 0, stream>>>(part, bl1, Wl2, bl2, out);
}